// Round 2
// baseline (2868.799 us; speedup 1.0000x reference)
//
#include <hip/hip_runtime.h>

#define L_PAD 8192
#define HS    25
#define ES    50
#define G4    100   // 4*H
#define LOG2E 1.44269504088896340736f

// -------- workspace layout --------
// zs2   : float2[2][L_PAD*50]   packed gate preacts: zs2[d][t*50+j] = (z[j], z[j+50])
// wstar : float2[2][50]         h* @ Wh, same packing
// cstar : float [2][25]         frozen cell state

typedef float f4 __attribute__((ext_vector_type(4)));

__device__ __forceinline__ float rl_f(float v, int lane) {
    return __int_as_float(__builtin_amdgcn_readlane(__float_as_int(v), lane));
}
__device__ __forceinline__ float fast_sigmoid(float x) {
    return __builtin_amdgcn_rcpf(1.f + __builtin_amdgcn_exp2f(x * (-LOG2E)));
}
__device__ __forceinline__ float fast_tanh(float x) {
    // 2*sigmoid(2x) - 1
    return fmaf(__builtin_amdgcn_rcpf(1.f + __builtin_amdgcn_exp2f(x * (-2.f * LOG2E))), 2.f, -1.f);
}

// ---------------- kernel 1: pre-activations (parallel) ----------------
__global__ __launch_bounds__(64) void k_pre(
    const int* __restrict__ tok, const int* __restrict__ plen,
    const float* __restrict__ Ef, const float* __restrict__ Wif, const float* __restrict__ bf,
    const float* __restrict__ Eb, const float* __restrict__ Wib, const float* __restrict__ bb,
    float2* __restrict__ zs2)
{
    const int b = blockIdx.x;
    const int d = b & 1;
    const int t = b >> 1;
    const int j = threadIdx.x;
    const int len = *plen;

    int src;
    if (d == 0) src = t;
    else        src = (t < len) ? (len - 1 - t) : (L_PAD - 1 - (t - len));
    const int token = tok[src];

    const float* __restrict__ E  = d ? Eb  : Ef;
    const float* __restrict__ Wi = d ? Wib : Wif;
    const float* __restrict__ bs = d ? bb  : bf;

    __shared__ float e[ES];
    if (j < ES) e[j] = E[(size_t)token * ES + j];
    __syncthreads();
    if (j >= 50) return;

    float ax = bs[j], ay = bs[j + 50];
    float bx = 0.f,  by = 0.f;
    #pragma unroll
    for (int k = 0; k < ES; k += 2) {
        float e0 = e[k], e1 = e[k + 1];
        ax = fmaf(e0, Wi[k * G4 + j],            ax);
        ay = fmaf(e0, Wi[k * G4 + j + 50],       ay);
        bx = fmaf(e1, Wi[(k + 1) * G4 + j],      bx);
        by = fmaf(e1, Wi[(k + 1) * G4 + j + 50], by);
    }
    zs2[(size_t)d * (L_PAD * 50) + t * 50 + j] = make_float2(ax + bx, ay + by);
}

// ---------------- kernel 2: the serial recurrence (latency-bound) ----------------
// one wave per direction. lane j in [0,50): gates (j, j+50).
//   lanes 0..24  -> (i_k, g_k),  lanes 25..49 -> (f_k, o_k)
//
// Round-5 theory (unchanged): VGPR_Count=40 < 50 pinned weights + active-CU VALU
// issue ~11% -> the RA spilled the weights to scratch; every serial step pays
// clustered L1 reload latency (~90% stall). Fix = stop fighting the RA:
//  * weights live in LDS, per-lane-contiguous k-QUADS:
//      wq[lane][q] = (Wh[4q][col], Wh[4q+1][col], Wh[4q+2][col], Wh[4q+3][col])
//    (k padded 25->28 with zero rows). Re-read per step: 14 x ds_read_b128.
//    Per-lane stride 112B (7 quads; 7 coprime 8) -> conflict-light.
//  * an empty asm on the LDS index defeats LICM so the 28 float4s are never
//    hoisted into 112 live VGPRs (the original spill trigger).
//  * readlane(h, 25..27) touches garbage lanes, but h = o*tanh(nc) is in
//    (-1,1) on EVERY lane, so 0-pad * finite == 0. No NaN path.
//  * plain float4 arithmetic only (round-5 v_pk_fma_f32 inline asm was the
//    prime suspect for the container failure: packed-FP32 VALU is unverified
//    on gfx950 and absent from the ISA doc).
#define MATVEC(PX, PY)                                                      \
    {                                                                       \
        int bi = jj;                                                        \
        asm volatile("" : "+v"(bi));  /* opaque: no hoisting LDS reads */   \
        const f4* __restrict__ wa = &wq[bi * 7];                            \
        const f4* __restrict__ wb = &wq[350 + bi * 7];                      \
        f4 accA0 = {0.f, 0.f, 0.f, 0.f}, accA1 = accA0;                     \
        f4 accB0 = accA0, accB1 = accA0;                                    \
        _Pragma("unroll")                                                   \
        for (int q = 0; q < 7; ++q) {                                       \
            f4 wva = wa[q];                                                 \
            f4 wvb = wb[q];                                                 \
            f4 hv;                                                          \
            hv.x = rl_f(h, 4 * q);                                          \
            hv.y = rl_f(h, 4 * q + 1);                                      \
            hv.z = rl_f(h, 4 * q + 2);                                      \
            hv.w = rl_f(h, 4 * q + 3);                                      \
            if (q & 1) { accA1 += wva * hv; accB1 += wvb * hv; }            \
            else       { accA0 += wva * hv; accB0 += wvb * hv; }            \
        }                                                                   \
        f4 sa4 = accA0 + accA1;                                             \
        f4 sb4 = accB0 + accB1;                                             \
        PX = (sa4.x + sa4.y) + (sa4.z + sa4.w);                             \
        PY = (sb4.x + sb4.y) + (sb4.z + sb4.w);                             \
    }

__global__ __launch_bounds__(64, 1)
void k_seq(
    const float* __restrict__ Whf, const float* __restrict__ Whb,
    const int* __restrict__ plen,
    const float2* __restrict__ zs2_all,
    float* __restrict__ out,
    float2* __restrict__ wstar, float* __restrict__ cstar)
{
    __shared__ f4 wq[2 * 50 * 7];   // [0,350): A-side (col j); [350,700): B-side (col j+50)

    const int d = blockIdx.x;
    const int j = threadIdx.x;
    const int len = *plen;
    const float* __restrict__ Wh = d ? Whb : Whf;
    const int jj = (j < 50) ? j : 0;

    // build packed weight LDS (once): quad q of lane j = Wh[4q..4q+3][j / j+50]
    if (j < 50) {
        #pragma unroll
        for (int q = 0; q < 7; ++q) {
            f4 a = {0.f, 0.f, 0.f, 0.f}, b = a;
            #pragma unroll
            for (int u = 0; u < 4; ++u) {
                int k = 4 * q + u;
                if (k < 25) {
                    a[u] = Wh[k * G4 + j];
                    b[u] = Wh[k * G4 + j + 50];
                }
            }
            wq[j * 7 + q]       = a;
            wq[350 + j * 7 + q] = b;
        }
    }
    __syncthreads();

    // branch-free activation constants: second gate is tanh for lanes<25, sigmoid otherwise
    const bool  isG = (j < 25);
    const float my = isG ? (-2.f * LOG2E) : (-LOG2E);
    const float ca = isG ? 2.f : 1.f;
    const float cb = isG ? -1.f : 0.f;
    const int perm = ((j + 25) & 63) << 2;      // ds_bpermute byte address, lane j+25

    const float2* __restrict__ zb = zs2_all + (size_t)d * (L_PAD * 50) + jj;
    float* outp = out + d * HS + j;             // stride 50 floats per step

    float c = 0.f, h = 0.f;   // lanes 0..24 carry real state; all lanes' h stays in (-1,1)
    // prefetch pipeline, distance 4 (zs2 mostly in remote-XCD L2 / L3: ~400-600 cyc)
    float2 z0 = zb[0], z1 = zb[50], z2 = zb[100], z3 = zb[150];

    for (int t = 0; t < len; ++t) {
        int tp = t + 4; tp = (tp < L_PAD) ? tp : (L_PAD - 1);
        float2 zf = zb[tp * 50];

        float px, py;
        MATVEC(px, py)
        px += z0.x;
        py += z0.y;

        float sa = fast_sigmoid(px);             // i (lanes<25) / f (lanes>=25)
        float ry = __builtin_amdgcn_rcpf(1.f + __builtin_amdgcn_exp2f(py * my));
        float sb = fmaf(ry, ca, cb);             // g=tanh (lanes<25) / o=sigmoid
        float f_ = __int_as_float(__builtin_amdgcn_ds_bpermute(perm, __float_as_int(sa)));
        float o_ = __int_as_float(__builtin_amdgcn_ds_bpermute(perm, __float_as_int(sb)));
        float nc = fmaf(f_, c, sa * sb);         // f*c + i*g
        float nh = o_ * fast_tanh(nc);
        c = nc;                                  // unconditional: every lane's nh is
        h = nh;                                  //  bounded by tanh -> finite forever
        if (j < 25) outp[t * 50] = nh;           // out[t*50 + d*25 + j]
        z0 = z1; z1 = z2; z2 = z3; z3 = zf;
    }

    // epilogue: w* = h* @ Wh (packed) and c* for the frozen tail
    {
        float ex, ey;
        MATVEC(ex, ey)
        if (j < 50) wstar[d * 50 + j] = make_float2(ex, ey);
        if (j < 25) cstar[d * HS + j] = c;
    }
}

// ---------------- kernel 3: frozen-carry tail (parallel) ----------------
__global__ __launch_bounds__(256) void k_tail(
    const int* __restrict__ plen,
    const float2* __restrict__ zs2_all,
    const float2* __restrict__ wstar, const float* __restrict__ cstar,
    float* __restrict__ out)
{
    const int tid = blockIdx.x * 256 + threadIdx.x;
    if (tid >= L_PAD * 50) return;
    const int col = tid % 50;
    const int t   = tid / 50;
    const int len = *plen;
    if (t < len) return;
    const int d = col / HS;
    const int j = col % HS;

    const float2* __restrict__ z = zs2_all + (size_t)d * (L_PAD * 50);
    float2 zi = z[t * 50 + j];
    float2 zq = z[t * 50 + j + 25];
    float2 wi = wstar[d * 50 + j];
    float2 wq = wstar[d * 50 + j + 25];

    float i_ = fast_sigmoid(zi.x + wi.x);
    float g_ = fast_tanh  (zi.y + wi.y);
    float f_ = fast_sigmoid(zq.x + wq.x);
    float o_ = fast_sigmoid(zq.y + wq.y);

    float nc = fmaf(f_, cstar[d * HS + j], i_ * g_);
    out[t * 50 + col] = o_ * fast_tanh(nc);
}

extern "C" void kernel_launch(void* const* d_in, const int* in_sizes, int n_in,
                              void* d_out, int out_size, void* d_ws, size_t ws_size,
                              hipStream_t stream)
{
    const int*   tok  = (const int*)  d_in[0];
    const int*   plen = (const int*)  d_in[1];
    const float* Ef   = (const float*)d_in[2];
    const float* Wif  = (const float*)d_in[3];
    const float* Whf  = (const float*)d_in[4];
    const float* bf   = (const float*)d_in[5];
    const float* Eb   = (const float*)d_in[6];
    const float* Wib  = (const float*)d_in[7];
    const float* Whb  = (const float*)d_in[8];
    const float* bb   = (const float*)d_in[9];
    float* out = (float*)d_out;

    float2* zs2   = (float2*)d_ws;
    float2* wstar = (float2*)((char*)d_ws + (size_t)2 * L_PAD * 50 * sizeof(float2));
    float*  cstar = (float*)((char*)wstar + 100 * sizeof(float2));

    k_pre <<<2 * L_PAD, 64, 0, stream>>>(tok, plen, Ef, Wif, bf, Eb, Wib, bb, zs2);
    k_seq <<<2, 64, 0, stream>>>(Whf, Whb, plen, zs2, out, wstar, cstar);
    k_tail<<<(L_PAD * 50 + 255) / 256, 256, 0, stream>>>(plen, zs2, wstar, cstar, out);
}

// Round 3
// 2499.301 us; speedup vs baseline: 1.1478x; 1.1478x over previous
//
#include <hip/hip_runtime.h>

#define L_PAD 8192
#define HS    25
#define ES    50
#define G4    100   // 4*H
#define CHUNK 64    // z-staging chunk (steps); 64*50 float2 = 25600 B = 25 lds-DMA instrs
#define LOG2E 1.44269504088896340736f

// -------- workspace layout --------
// zs2   : float2[2][L_PAD*50]   packed gate preacts: zs2[d][t*50+j] = (z[j], z[j+50])
// wstar : float2[2][50]         h* @ Wh, same packing
// cstar : float [2][25]         frozen cell state

__device__ __forceinline__ float rl_f(float v, int lane) {
    return __int_as_float(__builtin_amdgcn_readlane(__float_as_int(v), lane));
}
__device__ __forceinline__ float fast_sigmoid(float x) {
    return __builtin_amdgcn_rcpf(1.f + __builtin_amdgcn_exp2f(x * (-LOG2E)));
}
__device__ __forceinline__ float fast_tanh(float x) {
    // 2*sigmoid(2x) - 1
    return fmaf(__builtin_amdgcn_rcpf(1.f + __builtin_amdgcn_exp2f(x * (-2.f * LOG2E))), 2.f, -1.f);
}

// ---------------- kernel 1: pre-activations (parallel) ----------------
__global__ __launch_bounds__(64) void k_pre(
    const int* __restrict__ tok, const int* __restrict__ plen,
    const float* __restrict__ Ef, const float* __restrict__ Wif, const float* __restrict__ bf,
    const float* __restrict__ Eb, const float* __restrict__ Wib, const float* __restrict__ bb,
    float2* __restrict__ zs2)
{
    const int b = blockIdx.x;
    const int d = b & 1;
    const int t = b >> 1;
    const int j = threadIdx.x;
    const int len = *plen;

    int src;
    if (d == 0) src = t;
    else        src = (t < len) ? (len - 1 - t) : (L_PAD - 1 - (t - len));
    const int token = tok[src];

    const float* __restrict__ E  = d ? Eb  : Ef;
    const float* __restrict__ Wi = d ? Wib : Wif;
    const float* __restrict__ bs = d ? bb  : bf;

    __shared__ float e[ES];
    if (j < ES) e[j] = E[(size_t)token * ES + j];
    __syncthreads();
    if (j >= 50) return;

    float ax = bs[j], ay = bs[j + 50];
    float bx = 0.f,  by = 0.f;
    #pragma unroll
    for (int k = 0; k < ES; k += 2) {
        float e0 = e[k], e1 = e[k + 1];
        ax = fmaf(e0, Wi[k * G4 + j],            ax);
        ay = fmaf(e0, Wi[k * G4 + j + 50],       ay);
        bx = fmaf(e1, Wi[(k + 1) * G4 + j],      bx);
        by = fmaf(e1, Wi[(k + 1) * G4 + j + 50], by);
    }
    zs2[(size_t)d * (L_PAD * 50) + t * 50 + j] = make_float2(ax + bx, ay + by);
}

// ---------------- kernel 2: the serial recurrence (latency-bound) ----------------
// one wave per direction. lane j in [0,50): gates (j, j+50).
//   lanes 0..24  -> (i_k, g_k),  lanes 25..49 -> (f_k, o_k)
//
// Round-6 theory: the shared round-0/round-2 stall is the per-step global z
// load: a rotating register prefetch forces a conservative s_waitcnt vmcnt(0)
// every iteration, exposing remote-XCD L2/L3 latency (~600-900 cyc) per step.
// Round 2 additionally paid ~7-way LDS bank conflicts (112B lane stride) =
// 336K conflict cycles. Fixes:
//  * z staged per 64-step CHUNK via 25x global_load_lds (direct-to-LDS DMA,
//    no VGPR round-trip), double-buffered; ONE vmcnt(0) per chunk, issued
//    after 64 steps of compute have hidden the latency (~11 cyc/step).
//  * weights in LDS, row-major k-pairs wl[kk][col] (row 800B): worst-case
//    3-way conflict ({j,j+16,j+32}), ~1.3x on ds_read_b64 per m136.
//  * LICM-opacity asm on the lane index so the 26 weight float2s are never
//    hoisted into 52 live VGPRs (the round-0 spill trigger).
__global__ __launch_bounds__(64, 1)
void k_seq(
    const float* __restrict__ Whf, const float* __restrict__ Whb,
    const int* __restrict__ plen,
    const float2* __restrict__ zs2_all,
    float* __restrict__ out,
    float2* __restrict__ wstar, float* __restrict__ cstar)
{
    __shared__ float2 wl[13 * 100];          // wl[kk*100+col] = (Wh[2kk][col], Wh[2kk+1][col]); kk=12 y=0 pad
    __shared__ float4 zch[2][CHUNK * 25];    // double-buffered z chunks: 2 x 25600 B

    const int d = blockIdx.x;
    const int j = threadIdx.x;
    const int len = *plen;
    const float* __restrict__ Wh = d ? Whb : Whf;
    const int jj = (j < 50) ? j : 0;

    // build packed weight LDS (once)
    if (j < 50) {
        #pragma unroll
        for (int kk = 0; kk < 13; ++kk) {
            float ax = Wh[(2 * kk) * G4 + j];
            float bx = Wh[(2 * kk) * G4 + j + 50];
            float ay = 0.f, by = 0.f;
            if (kk < 12) {
                ay = Wh[(2 * kk + 1) * G4 + j];
                by = Wh[(2 * kk + 1) * G4 + j + 50];
            }
            wl[kk * 100 + j]      = make_float2(ax, ay);
            wl[kk * 100 + j + 50] = make_float2(bx, by);
        }
    }
    __syncthreads();

    // branch-free activation constants: second gate is tanh for lanes<25, sigmoid otherwise
    const bool  isG = (j < 25);
    const float my = isG ? (-2.f * LOG2E) : (-LOG2E);
    const float ca = isG ? 2.f : 1.f;
    const float cb = isG ? -1.f : 0.f;
    const int perm = ((j + 25) & 63) << 2;       // ds_bpermute byte address, lane j+25

    const float4* __restrict__ zf4 = (const float4*)(zs2_all + (size_t)d * (L_PAD * 50));
    float* outp = out + d * HS + j;              // stride 50 floats per step

    float c = 0.f, h = 0.f;   // lanes 0..24 carry real state; all lanes' values stay finite

    // ---- chunked z staging: 25 direct-to-LDS DMAs per chunk, lane L covers quad L+64i ----
    #define STAGE(BUF, CI)                                                              \
        {                                                                               \
            const float4* gsrc = zf4 + (size_t)(CI) * (CHUNK * 25) + j;                 \
            _Pragma("unroll")                                                           \
            for (int i = 0; i < 25; ++i) {                                              \
                __builtin_amdgcn_global_load_lds(                                       \
                    (const __attribute__((address_space(1))) unsigned int*)(gsrc + 64 * i), \
                    (__attribute__((address_space(3))) unsigned int*)(&zch[BUF][i * 64]),   \
                    16, 0, 0);                                                          \
            }                                                                           \
        }

    const int nch = (len + CHUNK - 1) / CHUNK;
    int buf = 0;
    if (nch > 0) {
        STAGE(0, 0)
        asm volatile("s_waitcnt vmcnt(0)" ::: "memory");
        __builtin_amdgcn_sched_barrier(0);
    }

    for (int ct = 0; ct < nch; ++ct) {
        if (ct + 1 < L_PAD / CHUNK) STAGE(buf ^ 1, ct + 1)   // prefetch next chunk (no wait)

        const int t0 = ct * CHUNK;
        const int ne = (len - t0 < CHUNK) ? (len - t0) : CHUNK;
        const float2* __restrict__ zc = (const float2*)zch[buf];

        for (int s = 0; s < ne; ++s) {
            int bi = jj;
            asm volatile("" : "+v"(bi));          // opaque: forbid hoisting the LDS weight reads
            const float2* __restrict__ wrow = wl + bi;

            float axE = 0.f, axO = 0.f, ayE = 0.f, ayO = 0.f;
            #pragma unroll
            for (int kk = 0; kk < 13; ++kk) {
                float2 wa = wrow[kk * 100];
                float2 wb = wrow[kk * 100 + 50];
                float h0 = rl_f(h, 2 * kk);
                float h1 = rl_f(h, 2 * kk + 1);   // kk=12 -> lane 25 garbage, x0 weight pad
                axE = fmaf(wa.x, h0, axE); axO = fmaf(wa.y, h1, axO);
                ayE = fmaf(wb.x, h0, ayE); ayO = fmaf(wb.y, h1, ayO);
            }
            float2 zt = zc[s * 50 + bi];
            float px = (axE + axO) + zt.x;
            float py = (ayE + ayO) + zt.y;

            float sa = fast_sigmoid(px);          // i (lanes<25) / f (lanes>=25)
            float ry = __builtin_amdgcn_rcpf(1.f + __builtin_amdgcn_exp2f(py * my));
            float sb = fmaf(ry, ca, cb);          // g=tanh (lanes<25) / o=sigmoid
            float f_ = __int_as_float(__builtin_amdgcn_ds_bpermute(perm, __float_as_int(sa)));
            float o_ = __int_as_float(__builtin_amdgcn_ds_bpermute(perm, __float_as_int(sb)));
            float nc = fmaf(f_, c, sa * sb);      // f*c + i*g
            float nh = o_ * fast_tanh(nc);
            c = nc;                               // unconditional: every lane's value stays
            h = nh;                               //  bounded (tanh/sigmoid) -> finite forever
            if (j < 25) outp[(t0 + s) * 50] = nh; // out[t*50 + d*25 + j]
        }

        // next chunk's DMAs landed long ago (64 steps of compute); drain cheaply
        asm volatile("s_waitcnt vmcnt(0)" ::: "memory");
        __builtin_amdgcn_sched_barrier(0);
        buf ^= 1;
    }

    // epilogue: w* = h* @ Wh (packed) and c* for the frozen tail
    {
        int bi = jj;
        asm volatile("" : "+v"(bi));
        const float2* __restrict__ wrow = wl + bi;
        float axE = 0.f, axO = 0.f, ayE = 0.f, ayO = 0.f;
        #pragma unroll
        for (int kk = 0; kk < 13; ++kk) {
            float2 wa = wrow[kk * 100];
            float2 wb = wrow[kk * 100 + 50];
            float h0 = rl_f(h, 2 * kk);
            float h1 = rl_f(h, 2 * kk + 1);
            axE = fmaf(wa.x, h0, axE); axO = fmaf(wa.y, h1, axO);
            ayE = fmaf(wb.x, h0, ayE); ayO = fmaf(wb.y, h1, ayO);
        }
        if (j < 50) wstar[d * 50 + j] = make_float2(axE + axO, ayE + ayO);
        if (j < 25) cstar[d * HS + j] = c;
    }
}

// ---------------- kernel 3: frozen-carry tail (parallel) ----------------
__global__ __launch_bounds__(256) void k_tail(
    const int* __restrict__ plen,
    const float2* __restrict__ zs2_all,
    const float2* __restrict__ wstar, const float* __restrict__ cstar,
    float* __restrict__ out)
{
    const int tid = blockIdx.x * 256 + threadIdx.x;
    if (tid >= L_PAD * 50) return;
    const int col = tid % 50;
    const int t   = tid / 50;
    const int len = *plen;
    if (t < len) return;
    const int d = col / HS;
    const int j = col % HS;

    const float2* __restrict__ z = zs2_all + (size_t)d * (L_PAD * 50);
    float2 zi = z[t * 50 + j];
    float2 zq = z[t * 50 + j + 25];
    float2 wi = wstar[d * 50 + j];
    float2 wq = wstar[d * 50 + j + 25];

    float i_ = fast_sigmoid(zi.x + wi.x);
    float g_ = fast_tanh  (zi.y + wi.y);
    float f_ = fast_sigmoid(zq.x + wq.x);
    float o_ = fast_sigmoid(zq.y + wq.y);

    float nc = fmaf(f_, cstar[d * HS + j], i_ * g_);
    out[t * 50 + col] = o_ * fast_tanh(nc);
}

extern "C" void kernel_launch(void* const* d_in, const int* in_sizes, int n_in,
                              void* d_out, int out_size, void* d_ws, size_t ws_size,
                              hipStream_t stream)
{
    const int*   tok  = (const int*)  d_in[0];
    const int*   plen = (const int*)  d_in[1];
    const float* Ef   = (const float*)d_in[2];
    const float* Wif  = (const float*)d_in[3];
    const float* Whf  = (const float*)d_in[4];
    const float* bf   = (const float*)d_in[5];
    const float* Eb   = (const float*)d_in[6];
    const float* Wib  = (const float*)d_in[7];
    const float* Whb  = (const float*)d_in[8];
    const float* bb   = (const float*)d_in[9];
    float* out = (float*)d_out;

    float2* zs2   = (float2*)d_ws;
    float2* wstar = (float2*)((char*)d_ws + (size_t)2 * L_PAD * 50 * sizeof(float2));
    float*  cstar = (float*)((char*)wstar + 100 * sizeof(float2));

    k_pre <<<2 * L_PAD, 64, 0, stream>>>(tok, plen, Ef, Wif, bf, Eb, Wib, bb, zs2);
    k_seq <<<2, 64, 0, stream>>>(Whf, Whb, plen, zs2, out, wstar, cstar);
    k_tail<<<(L_PAD * 50 + 255) / 256, 256, 0, stream>>>(plen, zs2, wstar, cstar, out);
}